// Round 8
// baseline (1347.617 us; speedup 1.0000x reference)
//
#include <hip/hip_runtime.h>

#define BB 256
#define TT 1024
#define KK 64

__device__ __forceinline__ float rlane(float v, int lane) {
  return __int_as_float(__builtin_amdgcn_readlane(__float_as_int(v), lane));
}

// ---------------------------------------------------------------------------
// Chain kernel: grid 512 x 128. No LDS, no barriers anywhere.
//  blocks [0,256):   wave0 = forward logsumexp chain (readlane broadcast);
//                    wave1 = path score.
//  blocks [256,512): wave0 = Viterbi VALUE chain, dumps delta rows to ws;
//                    wave1 exits. Backpointers recomputed later in parallel.
// ---------------------------------------------------------------------------
__global__ __launch_bounds__(128, 1) void crf_chain_kernel(
    const float* __restrict__ em, const int* __restrict__ mask,
    const float* __restrict__ trans, const int* __restrict__ tags,
    float* __restrict__ wsdelta, float* ll_sum, int* maskSum) {
  const int role = (blockIdx.x >= BB) ? 1 : 0;
  const int b = blockIdx.x & (BB - 1);
  const int tid = threadIdx.x;
  const int wv = tid >> 6;
  const int l = tid & 63;

  const float* emb = em + (size_t)b * TT * KK;
  const int* mb = mask + (size_t)b * TT;

  if (wv == 1) {
    if (role == 1) return;
    // ---------------- path score (independent wave) ----------------
    const int* tgb = tags + (size_t)b * TT;
    float acc = 0.f;
    int cnt = 0;
    for (int t = l; t < TT; t += 64) {
      if (mb[t]) {
        int tg = tgb[t];
        acc += emb[(size_t)t * KK + tg];
        cnt += 1;
        if (t >= 1) acc += trans[tgb[t - 1] * KK + tg];
      }
    }
#pragma unroll
    for (int o = 1; o <= 32; o <<= 1) {
      acc += __shfl_xor(acc, o);
      cnt += __shfl_xor(cnt, o);
    }
    if (l == 0) { atomicAdd(ll_sum, acc); atomicAdd(maskSum, cnt); }
    return;
  }

  const int j = l;
  // prefetch rings (emissions + mask), depth 8
  float ep[8];
  int mk[8];
#pragma unroll
  for (int k = 0; k < 8; ++k) {
    ep[k] = emb[(size_t)(1 + k) * KK + j];
    mk[k] = mb[1 + k];
  }

  if (role == 0) {
    // =========================== FORWARD ===========================
    float E[KK];
#pragma unroll
    for (int r = 0; r < KK; ++r) E[r] = __expf(trans[r * KK + j]);

    float e0 = emb[j];
    float gm0 = e0;
#pragma unroll
    for (int o = 1; o <= 32; o <<= 1) gm0 = fmaxf(gm0, __shfl_xor(gm0, o));
    float s = __expf(e0 - gm0);
    float offset = gm0;

    auto step = [&](int t, float e, int m, bool ren) {
      float q0 = 0.f, q1 = 0.f, q2 = 0.f, q3 = 0.f;
      float q4 = 0.f, q5 = 0.f, q6 = 0.f, q7 = 0.f;
      float gmax = -3.402823e38f;
#pragma unroll
      for (int r = 0; r < KK; r += 8) {
        float s0 = rlane(s, r),     s1 = rlane(s, r + 1);
        float s2 = rlane(s, r + 2), s3 = rlane(s, r + 3);
        float s4 = rlane(s, r + 4), s5 = rlane(s, r + 5);
        float s6 = rlane(s, r + 6), s7 = rlane(s, r + 7);
        q0 = fmaf(s0, E[r],     q0); q1 = fmaf(s1, E[r + 1], q1);
        q2 = fmaf(s2, E[r + 2], q2); q3 = fmaf(s3, E[r + 3], q3);
        q4 = fmaf(s4, E[r + 4], q4); q5 = fmaf(s5, E[r + 5], q5);
        q6 = fmaf(s6, E[r + 6], q6); q7 = fmaf(s7, E[r + 7], q7);
        if (ren) {
          gmax = fmaxf(gmax, fmaxf(fmaxf(fmaxf(s0, s1), fmaxf(s2, s3)),
                                   fmaxf(fmaxf(s4, s5), fmaxf(s6, s7))));
        }
      }
      float q = ((q0 + q1) + (q2 + q3)) + ((q4 + q5) + (q6 + q7));
      q *= __expf(e);
      q = m ? q : s;
      if (ren) {  // t ≡ 0 (mod 8): uniform rescale, tracked in offset
        q *= __builtin_amdgcn_rcpf(gmax);
        offset += __logf(gmax);
      }
      s = q;
    };

    for (int tb = 1; tb + 7 <= TT - 1; tb += 8) {
#pragma unroll
      for (int k = 0; k < 8; ++k) {
        int t = tb + k;
        float e = ep[k];
        int m = mk[k];
        int tp = t + 8;
        if (tp > TT - 1) tp = TT - 1;   // clamp (slot unused in tail)
        ep[k] = emb[(size_t)tp * KK + j];
        mk[k] = mb[tp];
        step(t, e, m, k == 7);          // tb≡1 (mod 8) -> t≡0 (mod 8) at k=7
      }
    }
#pragma unroll
    for (int k = 0; k < 7; ++k) step(1017 + k, ep[k], mk[k], false);

    float ss = s;
#pragma unroll
    for (int o = 1; o <= 32; o <<= 1) ss += __shfl_xor(ss, o);
    if (l == 0) atomicAdd(ll_sum, -(offset + __logf(ss)));
  } else {
    // ================= VITERBI (values only, dump rows) =================
    float C[KK];
#pragma unroll
    for (int r = 0; r < KK; ++r) C[r] = trans[r * KK + j];

    float d = emb[j];  // delta0
    float* wr = wsdelta + (size_t)b * TT * KK;
    wr[j] = d;         // row 0

    auto vstep = [&](int t, float e, int m) {
      float m0 = -3.402823e38f, m1 = m0, m2 = m0, m3 = m0;
#pragma unroll
      for (int r = 0; r < KK; r += 8) {
        float v0 = rlane(d, r)     + C[r];
        float v1 = rlane(d, r + 1) + C[r + 1];
        float v2 = rlane(d, r + 2) + C[r + 2];
        float v3 = rlane(d, r + 3) + C[r + 3];
        float v4 = rlane(d, r + 4) + C[r + 4];
        float v5 = rlane(d, r + 5) + C[r + 5];
        float v6 = rlane(d, r + 6) + C[r + 6];
        float v7 = rlane(d, r + 7) + C[r + 7];
        m0 = fmaxf(m0, fmaxf(v0, v1));  // folds to v_max3_f32
        m1 = fmaxf(m1, fmaxf(v2, v3));
        m2 = fmaxf(m2, fmaxf(v4, v5));
        m3 = fmaxf(m3, fmaxf(v6, v7));
      }
      float best = fmaxf(fmaxf(m0, m1), fmaxf(m2, m3));
      d = m ? (best + e) : d;
      wr[(size_t)t * KK + j] = d;  // fire-and-forget
    };

    for (int tb = 1; tb + 7 <= TT - 1; tb += 8) {
#pragma unroll
      for (int k = 0; k < 8; ++k) {
        int t = tb + k;
        float e = ep[k];
        int m = mk[k];
        int tp = t + 8;
        if (tp > TT - 1) tp = TT - 1;
        ep[k] = emb[(size_t)tp * KK + j];
        mk[k] = mb[tp];
        vstep(t, e, m);
      }
    }
#pragma unroll
    for (int k = 0; k < 7; ++k) vstep(1017 + k, ep[k], mk[k]);
  }
}

// ---------------------------------------------------------------------------
// BP-recompute + backtrace: grid 256 x 512. Parallel over t (8 waves/batch).
// Exact fp32 adds from stored rows -> bit-identical values; ordered-adjacent
// tournament -> numpy first-occurrence argmax.
// ---------------------------------------------------------------------------
__global__ __launch_bounds__(512, 2) void crf_bp_kernel(
    const float* __restrict__ wsdelta, const int* __restrict__ mask,
    const float* __restrict__ trans, const int* __restrict__ tags,
    float* __restrict__ out_dec, int* match) {
  __shared__ unsigned char bpl[TT][KK];   // 64 KB
  __shared__ unsigned char mrow[TT];
  __shared__ unsigned char segm[32][KK];
  __shared__ unsigned char bs[40];
  __shared__ int redm[32];

  const int b = blockIdx.x;
  const int tid = threadIdx.x;
  const int l = tid & 63;
  const int w = tid >> 6;  // 0..7

  const int* mb = mask + (size_t)b * TT;
  const int* tgb = tags + (size_t)b * TT;
  const float* rp = wsdelta + (size_t)b * TT * KK;

  float C[KK];
#pragma unroll
  for (int r = 0; r < KK; ++r) C[r] = trans[r * KK + l];
  for (int t = tid; t < TT; t += 512) mrow[t] = (unsigned char)(mb[t] ? 1 : 0);
  __syncthreads();

  for (int t = 1 + w; t <= TT - 1; t += 8) {
    const float4* rv = reinterpret_cast<const float4*>(rp + (size_t)(t - 1) * KK);
    float vv[KK];
#pragma unroll
    for (int k = 0; k < 16; ++k) {
      float4 x = rv[k];
      vv[4 * k]     = x.x + C[4 * k];
      vv[4 * k + 1] = x.y + C[4 * k + 1];
      vv[4 * k + 2] = x.z + C[4 * k + 2];
      vv[4 * k + 3] = x.w + C[4 * k + 3];
    }
    // ordered-adjacent tournament: ties -> lower index (numpy argmax)
    float tv[32]; int ti[32];
#pragma unroll
    for (int k = 0; k < 32; ++k) {
      bool tk = vv[2 * k + 1] > vv[2 * k];
      tv[k] = tk ? vv[2 * k + 1] : vv[2 * k];
      ti[k] = tk ? 2 * k + 1 : 2 * k;
    }
#pragma unroll
    for (int width = 16; width >= 1; width >>= 1) {
#pragma unroll
      for (int k = 0; k < 16; ++k) {
        if (k < width) {
          bool tk = tv[2 * k + 1] > tv[2 * k];
          tv[k] = tk ? tv[2 * k + 1] : tv[2 * k];
          ti[k] = tk ? ti[2 * k + 1] : ti[2 * k];
        }
      }
    }
    int bp = mrow[t] ? ti[0] : l;
    bpl[t][l] = (unsigned char)bp;
  }
  __syncthreads();

  // compose 32-step maps: 2048 chains over 512 threads (4 each)
  {
    int j0 = tid & 63;
    int sh = tid >> 6;  // 0..7; chains s = sh + 8*kk
    int xs[4], tEnd[4], tStart[4];
#pragma unroll
    for (int kk = 0; kk < 4; ++kk) {
      int s = sh + 8 * kk;
      xs[kk] = j0;
      tStart[kk] = 32 * s + 1;
      tEnd[kk] = (s == 31) ? (TT - 1) : (32 * s + 32);
    }
    for (int q = 0; q < 32; ++q) {
#pragma unroll
      for (int kk = 0; kk < 4; ++kk) {
        int t = tEnd[kk] - q;
        if (t >= tStart[kk]) xs[kk] = bpl[t][xs[kk]];
      }
    }
#pragma unroll
    for (int kk = 0; kk < 4; ++kk)
      segm[sh + 8 * kk][tid & 63] = (unsigned char)xs[kk];
  }
  __syncthreads();

  if (tid < 64) {  // last_tag: butterfly argmax over final row, low-idx ties
    float best = rp[(size_t)(TT - 1) * KK + tid];
    int bidx = tid;
#pragma unroll
    for (int o = 1; o <= 32; o <<= 1) {
      float ob = __shfl_xor(best, o);
      int oi = __shfl_xor(bidx, o);
      bool take = (ob > best) || ((ob == best) && (oi < bidx));
      best = take ? ob : best;
      bidx = take ? oi : bidx;
    }
    if (tid == 0) {
      unsigned char x = (unsigned char)bidx;
      bs[32] = x;
      for (int s = 31; s >= 0; --s) { x = segm[s][x]; bs[s] = x; }
    }
  }
  __syncthreads();

  if (tid < 32) {  // per-segment backtrace
    int s = tid;
    int x = bs[s + 1];
    int cnt = 0;
    int tEnd = (s == 31) ? (TT - 1) : (32 * s + 32);
    if (s == 31) {
      int m = mrow[TT - 1];
      out_dec[(size_t)b * TT + TT - 1] = (float)(m ? x : 0);
      cnt += (m && x == tgb[TT - 1]);
    }
    for (int t = tEnd; t >= 32 * s + 1; --t) {
      x = bpl[t][x];
      int m2 = mrow[t - 1];
      out_dec[(size_t)b * TT + t - 1] = (float)(m2 ? x : 0);
      cnt += (m2 && x == tgb[t - 1]);
    }
    redm[s] = cnt;
  }
  __syncthreads();
  if (tid == 0) {
    int c = 0;
    for (int s = 0; s < 32; ++s) c += redm[s];
    atomicAdd(match, c);
  }
}

__global__ void finalize_kernel(const float* ll_sum, const int* match,
                                const int* maskSum, float* d_out) {
  d_out[0] = -(*ll_sum) / (float)BB;
  d_out[1 + BB * TT] = (float)(*match) / (float)(*maskSum);
}

extern "C" void kernel_launch(void* const* d_in, const int* in_sizes, int n_in,
                              void* d_out, int out_size, void* d_ws, size_t ws_size,
                              hipStream_t stream) {
  const float* em = (const float*)d_in[0];
  const int* tags = (const int*)d_in[1];
  const int* mask = (const int*)d_in[2];       // bool -> int32 on device
  const float* trans = (const float*)d_in[3];
  float* out = (float*)d_out;

  const size_t dbytes = (size_t)BB * TT * KK * sizeof(float);  // 64 MB
  float* wsdelta = (float*)d_ws;
  float* ll_sum = (float*)((char*)d_ws + dbytes);
  int* match = (int*)((char*)d_ws + dbytes + 4);
  int* maskSum = (int*)((char*)d_ws + dbytes + 8);

  hipMemsetAsync((char*)d_ws + dbytes, 0, 12, stream);
  crf_chain_kernel<<<2 * BB, 128, 0, stream>>>(em, mask, trans, tags, wsdelta,
                                               ll_sum, maskSum);
  crf_bp_kernel<<<BB, 512, 0, stream>>>(wsdelta, mask, trans, tags, out + 1,
                                        match);
  finalize_kernel<<<1, 1, 0, stream>>>(ll_sum, match, maskSum, out);
}

// Round 9
// 737.536 us; speedup vs baseline: 1.8272x; 1.8272x over previous
//
#include <hip/hip_runtime.h>

#define BB 256
#define TT 1024
#define KK 64

// broadcast lane r's value to all lanes via ds_bpermute (VGPR dest, LDS pipe,
// pipelineable; avoids v_readlane's SGPR-recycle serialization seen in R8)
__device__ __forceinline__ float bcast(float v, int lane) {
  return __int_as_float(
      __builtin_amdgcn_ds_bpermute(lane << 2, __float_as_int(v)));
}

// ---------------------------------------------------------------------------
// Chain kernel: grid 512 x 128. No LDS storage, no barriers.
//  blocks [0,256):   wave0 = forward logsumexp chain; wave1 = path score.
//  blocks [256,512): wave0 = Viterbi VALUE chain, dumps delta rows to ws;
//                    wave1 exits. Backpointers recomputed later in parallel.
// ---------------------------------------------------------------------------
__global__ __launch_bounds__(128, 1) void crf_chain_kernel(
    const float* __restrict__ em, const int* __restrict__ mask,
    const float* __restrict__ trans, const int* __restrict__ tags,
    float* __restrict__ wsdelta, float* ll_sum, int* maskSum) {
  const int role = (blockIdx.x >= BB) ? 1 : 0;
  const int b = blockIdx.x & (BB - 1);
  const int tid = threadIdx.x;
  const int wv = tid >> 6;
  const int l = tid & 63;

  const float* emb = em + (size_t)b * TT * KK;
  const int* mb = mask + (size_t)b * TT;

  if (wv == 1) {
    if (role == 1) return;
    // ---------------- path score (independent wave) ----------------
    const int* tgb = tags + (size_t)b * TT;
    float acc = 0.f;
    int cnt = 0;
    for (int t = l; t < TT; t += 64) {
      if (mb[t]) {
        int tg = tgb[t];
        acc += emb[(size_t)t * KK + tg];
        cnt += 1;
        if (t >= 1) acc += trans[tgb[t - 1] * KK + tg];
      }
    }
#pragma unroll
    for (int o = 1; o <= 32; o <<= 1) {
      acc += __shfl_xor(acc, o);
      cnt += __shfl_xor(cnt, o);
    }
    if (l == 0) { atomicAdd(ll_sum, acc); atomicAdd(maskSum, cnt); }
    return;
  }

  const int j = l;
  float ep[8];
  int mk[8];
#pragma unroll
  for (int k = 0; k < 8; ++k) {
    ep[k] = emb[(size_t)(1 + k) * KK + j];
    mk[k] = mb[1 + k];
  }

  if (role == 0) {
    // =========================== FORWARD ===========================
    float E[KK];
#pragma unroll
    for (int r = 0; r < KK; ++r) E[r] = __expf(trans[r * KK + j]);

    float e0 = emb[j];
    float gm0 = e0;
#pragma unroll
    for (int o = 1; o <= 32; o <<= 1) gm0 = fmaxf(gm0, __shfl_xor(gm0, o));
    float s = __expf(e0 - gm0);
    float offset = gm0;

    auto step = [&](int t, float e, int m, bool ren) {
      float q0 = 0.f, q1 = 0.f, q2 = 0.f, q3 = 0.f;
      float q4 = 0.f, q5 = 0.f, q6 = 0.f, q7 = 0.f;
      float gmax = -3.402823e38f;
#pragma unroll
      for (int r = 0; r < KK; r += 8) {
        float s0 = bcast(s, r),     s1 = bcast(s, r + 1);
        float s2 = bcast(s, r + 2), s3 = bcast(s, r + 3);
        float s4 = bcast(s, r + 4), s5 = bcast(s, r + 5);
        float s6 = bcast(s, r + 6), s7 = bcast(s, r + 7);
        q0 = fmaf(s0, E[r],     q0); q1 = fmaf(s1, E[r + 1], q1);
        q2 = fmaf(s2, E[r + 2], q2); q3 = fmaf(s3, E[r + 3], q3);
        q4 = fmaf(s4, E[r + 4], q4); q5 = fmaf(s5, E[r + 5], q5);
        q6 = fmaf(s6, E[r + 6], q6); q7 = fmaf(s7, E[r + 7], q7);
        if (ren) {
          gmax = fmaxf(gmax, fmaxf(fmaxf(fmaxf(s0, s1), fmaxf(s2, s3)),
                                   fmaxf(fmaxf(s4, s5), fmaxf(s6, s7))));
        }
      }
      float q = ((q0 + q1) + (q2 + q3)) + ((q4 + q5) + (q6 + q7));
      q *= __expf(e);
      q = m ? q : s;
      if (ren) {  // t ≡ 0 (mod 8): uniform rescale, tracked in offset
        q *= __builtin_amdgcn_rcpf(gmax);
        offset += __logf(gmax);
      }
      s = q;
    };

    for (int tb = 1; tb + 7 <= TT - 1; tb += 8) {
#pragma unroll
      for (int k = 0; k < 8; ++k) {
        int t = tb + k;
        float e = ep[k];
        int m = mk[k];
        int tp = t + 8;
        if (tp > TT - 1) tp = TT - 1;
        ep[k] = emb[(size_t)tp * KK + j];
        mk[k] = mb[tp];
        step(t, e, m, k == 7);
      }
    }
#pragma unroll
    for (int k = 0; k < 7; ++k) step(1017 + k, ep[k], mk[k], false);

    float ss = s;
#pragma unroll
    for (int o = 1; o <= 32; o <<= 1) ss += __shfl_xor(ss, o);
    if (l == 0) atomicAdd(ll_sum, -(offset + __logf(ss)));
  } else {
    // ================= VITERBI (values only, dump rows) =================
    float C[KK];
#pragma unroll
    for (int r = 0; r < KK; ++r) C[r] = trans[r * KK + j];

    float d = emb[j];  // delta0
    float* wr = wsdelta + (size_t)b * TT * KK;
    wr[j] = d;

    auto vstep = [&](int t, float e, int m) {
      float m0 = -3.402823e38f, m1 = m0, m2 = m0, m3 = m0;
#pragma unroll
      for (int r = 0; r < KK; r += 8) {
        float v0 = bcast(d, r)     + C[r];
        float v1 = bcast(d, r + 1) + C[r + 1];
        float v2 = bcast(d, r + 2) + C[r + 2];
        float v3 = bcast(d, r + 3) + C[r + 3];
        float v4 = bcast(d, r + 4) + C[r + 4];
        float v5 = bcast(d, r + 5) + C[r + 5];
        float v6 = bcast(d, r + 6) + C[r + 6];
        float v7 = bcast(d, r + 7) + C[r + 7];
        m0 = fmaxf(m0, fmaxf(v0, v1));  // folds to v_max3_f32
        m1 = fmaxf(m1, fmaxf(v2, v3));
        m2 = fmaxf(m2, fmaxf(v4, v5));
        m3 = fmaxf(m3, fmaxf(v6, v7));
      }
      float best = fmaxf(fmaxf(m0, m1), fmaxf(m2, m3));
      d = m ? (best + e) : d;
      wr[(size_t)t * KK + j] = d;  // fire-and-forget
    };

    for (int tb = 1; tb + 7 <= TT - 1; tb += 8) {
#pragma unroll
      for (int k = 0; k < 8; ++k) {
        int t = tb + k;
        float e = ep[k];
        int m = mk[k];
        int tp = t + 8;
        if (tp > TT - 1) tp = TT - 1;
        ep[k] = emb[(size_t)tp * KK + j];
        mk[k] = mb[tp];
        vstep(t, e, m);
      }
    }
#pragma unroll
    for (int k = 0; k < 7; ++k) vstep(1017 + k, ep[k], mk[k]);
  }
}

// ---------------------------------------------------------------------------
// BP-recompute + backtrace: grid 256 x 256, __launch_bounds__(256,1) so the
// allocator has a 512-VGPR budget (R8's (512,2) bound capped it at 68 and
// spilled the tournament arrays -> 929us). Streamed group-of-8 argmax keeps
// ~90 regs live. Exact fp32 adds -> bit-identical values; strict > across
// groups + descending in-group scan = numpy first-occurrence argmax.
// ---------------------------------------------------------------------------
__global__ __launch_bounds__(256, 1) void crf_bp_kernel(
    const float* __restrict__ wsdelta, const int* __restrict__ mask,
    const float* __restrict__ trans, const int* __restrict__ tags,
    float* __restrict__ out_dec, int* match) {
  __shared__ unsigned char bpl[TT][KK];   // 64 KB
  __shared__ unsigned char mrow[TT];
  __shared__ unsigned char segm[32][KK];
  __shared__ unsigned char bs[40];
  __shared__ int redm[32];

  const int b = blockIdx.x;
  const int tid = threadIdx.x;
  const int l = tid & 63;
  const int w = tid >> 6;  // 0..3

  const int* mb = mask + (size_t)b * TT;
  const int* tgb = tags + (size_t)b * TT;
  const float* rp = wsdelta + (size_t)b * TT * KK;

  float C[KK];
#pragma unroll
  for (int r = 0; r < KK; ++r) C[r] = trans[r * KK + l];
  for (int t = tid; t < TT; t += 256) mrow[t] = (unsigned char)(mb[t] ? 1 : 0);
  __syncthreads();

  for (int t = 1 + w; t <= TT - 1; t += 4) {
    const float4* rv =
        reinterpret_cast<const float4*>(rp + (size_t)(t - 1) * KK);
    float4 xx[16];
#pragma unroll
    for (int k = 0; k < 16; ++k) xx[k] = rv[k];
    float best = -3.402823e38f;
    int bidx = 0;
#pragma unroll
    for (int g = 0; g < 8; ++g) {
      float4 x0 = xx[2 * g], x1 = xx[2 * g + 1];
      float v0 = x0.x + C[8 * g + 0];
      float v1 = x0.y + C[8 * g + 1];
      float v2 = x0.z + C[8 * g + 2];
      float v3 = x0.w + C[8 * g + 3];
      float v4 = x1.x + C[8 * g + 4];
      float v5 = x1.y + C[8 * g + 5];
      float v6 = x1.z + C[8 * g + 6];
      float v7 = x1.w + C[8 * g + 7];
      float mg = fmaxf(fmaxf(fmaxf(v0, v1), fmaxf(v2, v3)),
                       fmaxf(fmaxf(v4, v5), fmaxf(v6, v7)));
      int ii = 7;
      ii = (v6 == mg) ? 6 : ii;
      ii = (v5 == mg) ? 5 : ii;
      ii = (v4 == mg) ? 4 : ii;
      ii = (v3 == mg) ? 3 : ii;
      ii = (v2 == mg) ? 2 : ii;
      ii = (v1 == mg) ? 1 : ii;
      ii = (v0 == mg) ? 0 : ii;
      bool take = mg > best;        // strict: earliest group wins ties
      bidx = take ? (8 * g + ii) : bidx;
      best = take ? mg : best;
    }
    int bp = mrow[t] ? bidx : l;
    bpl[t][l] = (unsigned char)bp;
  }
  __syncthreads();

  // compose 32-step maps: 2048 chains over 256 threads (8 each)
  {
    int j0 = tid & 63;
    int sh = tid >> 6;  // 0..3; chains s = sh + 4*kk
    int xs[8], tEnd[8], tStart[8];
#pragma unroll
    for (int kk = 0; kk < 8; ++kk) {
      int s = sh + 4 * kk;
      xs[kk] = j0;
      tStart[kk] = 32 * s + 1;
      tEnd[kk] = (s == 31) ? (TT - 1) : (32 * s + 32);
    }
    for (int q = 0; q < 32; ++q) {
#pragma unroll
      for (int kk = 0; kk < 8; ++kk) {
        int t = tEnd[kk] - q;
        if (t >= tStart[kk]) xs[kk] = bpl[t][xs[kk]];
      }
    }
#pragma unroll
    for (int kk = 0; kk < 8; ++kk)
      segm[sh + 4 * kk][j0] = (unsigned char)xs[kk];
  }
  __syncthreads();

  if (tid < 64) {  // last_tag: butterfly argmax over final row, low-idx ties
    float best = rp[(size_t)(TT - 1) * KK + tid];
    int bidx = tid;
#pragma unroll
    for (int o = 1; o <= 32; o <<= 1) {
      float ob = __shfl_xor(best, o);
      int oi = __shfl_xor(bidx, o);
      bool take = (ob > best) || ((ob == best) && (oi < bidx));
      best = take ? ob : best;
      bidx = take ? oi : bidx;
    }
    if (tid == 0) {
      unsigned char x = (unsigned char)bidx;
      bs[32] = x;
      for (int s = 31; s >= 0; --s) { x = segm[s][x]; bs[s] = x; }
    }
  }
  __syncthreads();

  if (tid < 32) {  // per-segment backtrace
    int s = tid;
    int x = bs[s + 1];
    int cnt = 0;
    int tEnd = (s == 31) ? (TT - 1) : (32 * s + 32);
    if (s == 31) {
      int m = mrow[TT - 1];
      out_dec[(size_t)b * TT + TT - 1] = (float)(m ? x : 0);
      cnt += (m && x == tgb[TT - 1]);
    }
    for (int t = tEnd; t >= 32 * s + 1; --t) {
      x = bpl[t][x];
      int m2 = mrow[t - 1];
      out_dec[(size_t)b * TT + t - 1] = (float)(m2 ? x : 0);
      cnt += (m2 && x == tgb[t - 1]);
    }
    redm[s] = cnt;
  }
  __syncthreads();
  if (tid == 0) {
    int c = 0;
    for (int s = 0; s < 32; ++s) c += redm[s];
    atomicAdd(match, c);
  }
}

__global__ void finalize_kernel(const float* ll_sum, const int* match,
                                const int* maskSum, float* d_out) {
  d_out[0] = -(*ll_sum) / (float)BB;
  d_out[1 + BB * TT] = (float)(*match) / (float)(*maskSum);
}

extern "C" void kernel_launch(void* const* d_in, const int* in_sizes, int n_in,
                              void* d_out, int out_size, void* d_ws, size_t ws_size,
                              hipStream_t stream) {
  const float* em = (const float*)d_in[0];
  const int* tags = (const int*)d_in[1];
  const int* mask = (const int*)d_in[2];       // bool -> int32 on device
  const float* trans = (const float*)d_in[3];
  float* out = (float*)d_out;

  const size_t dbytes = (size_t)BB * TT * KK * sizeof(float);  // 64 MB
  float* wsdelta = (float*)d_ws;
  float* ll_sum = (float*)((char*)d_ws + dbytes);
  int* match = (int*)((char*)d_ws + dbytes + 4);
  int* maskSum = (int*)((char*)d_ws + dbytes + 8);

  hipMemsetAsync((char*)d_ws + dbytes, 0, 12, stream);
  crf_chain_kernel<<<2 * BB, 128, 0, stream>>>(em, mask, trans, tags, wsdelta,
                                               ll_sum, maskSum);
  crf_bp_kernel<<<BB, 256, 0, stream>>>(wsdelta, mask, trans, tags, out + 1,
                                        match);
  finalize_kernel<<<1, 1, 0, stream>>>(ll_sum, match, maskSum, out);
}